// Round 8
// baseline (524.643 us; speedup 1.0000x reference)
//
#include <hip/hip_runtime.h>
#include <hip/hip_bf16.h>
#include <math.h>

#define MTOK 16384   // B*N = 4*4096

typedef __attribute__((ext_vector_type(8))) short bf16x8;
typedef __attribute__((ext_vector_type(4))) float f32x4;
typedef __attribute__((ext_vector_type(16))) float f32x16;

__device__ __forceinline__ float bf2f(ushort u) {
  union { unsigned int u; float f; } c; c.u = ((unsigned int)u) << 16; return c.f;
}
__device__ __forceinline__ ushort f2bf(float f) {
  union { float f; unsigned int u; } c; c.f = f;
  unsigned int r = c.u + 0x7fffu + ((c.u >> 16) & 1u);
  return (ushort)(r >> 16);
}

__device__ __forceinline__ void gload_lds16(const void* g, void* l) {
  __builtin_amdgcn_global_load_lds(
      (const __attribute__((address_space(1))) unsigned int*)g,
      (__attribute__((address_space(3))) unsigned int*)l, 16, 0, 0);
}

// ---------------- fp32 -> bf16 convert (weights) ----------------
__global__ __launch_bounds__(256)
void f32_to_bf16_k(const float* __restrict__ in, ushort* __restrict__ out, int n4) {
  int i = blockIdx.x * 256 + threadIdx.x;
  if (i >= n4) return;
  float4 v = *(const float4*)&in[(size_t)i * 4];
  ushort4 o;
  o.x = f2bf(v.x); o.y = f2bf(v.y); o.z = f2bf(v.z); o.w = f2bf(v.w);
  *(ushort4*)&out[(size_t)i * 4] = o;
}

// fp32 -> bf16 with per-ROW scale (folds gamma into weight rows): row = idx/K_in
__global__ __launch_bounds__(256)
void f32_to_bf16_rs_k(const float* __restrict__ in, ushort* __restrict__ out,
                      int n4, const float* __restrict__ rs, int K_in) {
  int i = blockIdx.x * 256 + threadIdx.x;
  if (i >= n4) return;
  float g = rs[(i * 4) / K_in];
  float4 v = *(const float4*)&in[(size_t)i * 4];
  ushort4 o;
  o.x = f2bf(v.x * g); o.y = f2bf(v.y * g); o.z = f2bf(v.z * g); o.w = f2bf(v.w * g);
  *(ushort4*)&out[(size_t)i * 4] = o;
}

// gb[c] = gamma[c] * bias[c]
__global__ __launch_bounds__(256)
void gbias_k(const float* __restrict__ gamma, const float* __restrict__ bias,
             float* __restrict__ gb, int n) {
  int i = blockIdx.x * 256 + threadIdx.x;
  if (i < n) gb[i] = gamma[i] * bias[i];
}

// rn[i] = (sqrt(1024)+eps)/sqrt(sumsq[i])
__global__ __launch_bounds__(256)
void rn_k(const float* __restrict__ sumsq, float* __restrict__ rn, int n) {
  int i = blockIdx.x * 256 + threadIdx.x;
  if (i < n) rn[i] = (32.0f + 1e-6f) / sqrtf(sumsq[i]);
}

// ---------------- RMSNorm: fp32 in -> bf16 out (branch 1 only) ----------------
__global__ __launch_bounds__(256)
void rmsnorm_k(const float* __restrict__ x, const float* __restrict__ scale,
               ushort* __restrict__ out) {
  __shared__ float red[4];
  int row = blockIdx.x;
  int t = threadIdx.x;
  const float* xr = x + (size_t)row * 1024;
  float4 v = *(const float4*)&xr[t * 4];
  float s = v.x*v.x + v.y*v.y + v.z*v.z + v.w*v.w;
  #pragma unroll
  for (int off = 32; off > 0; off >>= 1) s += __shfl_xor(s, off);
  if ((t & 63) == 0) red[t >> 6] = s;
  __syncthreads();
  float tot = red[0] + red[1] + red[2] + red[3];
  float rn = (32.0f + 1e-6f) / sqrtf(tot);
  float4 sc = *(const float4*)&scale[t * 4];
  ushort4 o;
  o.x = f2bf(v.x * rn * sc.x);
  o.y = f2bf(v.y * rn * sc.y);
  o.z = f2bf(v.z * rn * sc.z);
  o.w = f2bf(v.w * rn * sc.w);
  *(ushort4*)&out[(size_t)row * 1024 + t * 4] = o;
}

// ---------------- bf16 MFMA GEMM: out[M,F] = A[M,K] @ W[F,K]^T ----------------
// 128x128 tile, BK=32, 4 waves (2x2), wave tile 64x64 = 2x2 frags of 32x32x16.
// 2-phase LDS dbuf (R6-proven): stage(t+1) issued before MFMA of t, 1 barrier/tile.
// Granule-XOR swizzle on global SOURCE + ds_read (both-sides); T1 XCD chunking.
// A/B frag: row=lane&31, k=(lane>>5)*8 (by analogy w/ verified 16x16x32).
// C/D frag (m74/m101-verified): col=lane&31, row=(reg&3)+8*(reg>>2)+4*(lane>>5).
// EPI 0: qkv — q(phi) token-major; k(phi)/v transposed [b,h,ch,n]
// EPI 1: outf32 = resid + acc + gb[col]                     (conv2 final)
// EPI 2: gelu(acc*rowscale[row] + bias) bf16, tanh approx   (conv1, rn deferred)
// EPI 3: proj + norm-fusion: x1=resid+acc+gb; out f32; xnraw=bf16(x1*escale[col]);
//        per-row sum(x1^2) -> LDS atomic -> global atomic
template<int EPI>
__global__ __launch_bounds__(256, 2)
void gemm_bt(const ushort* __restrict__ A, const ushort* __restrict__ W,
             void* __restrict__ outp, const float* __restrict__ bias,
             const float* __restrict__ resid,
             ushort* __restrict__ kTp, ushort* __restrict__ vTp,
             const float* __restrict__ escale, const float* __restrict__ rowscale,
             float* __restrict__ sumsq, ushort* __restrict__ xnout,
             int M, int F, int K) {
  __shared__ ushort lA[2][128 * 32];
  __shared__ ushort lB[2][128 * 32];
  const int tid = threadIdx.x;
  const int lane = tid & 63;
  const int w = tid >> 6;
  const int nBn = F >> 7;
  // T1: XCD gets a contiguous bm-major chunk (bijective: grid%8==0)
  const int cpx = (int)gridDim.x >> 3;
  const int tile = ((int)blockIdx.x & 7) * cpx + ((int)blockIdx.x >> 3);
  const int bm = tile / nBn;
  const int bn = tile % nBn;
  const int brow = bm << 7, bcol = bn << 7;
  const int wr = w >> 1, wc = w & 1;

  const int srow = (w << 4) + (lane >> 2);
  const int key = (srow >> 1) & 3;
  const int kcsrc = (lane & 3) ^ key;
  const ushort* gA0 = A + (size_t)(brow + srow) * K + kcsrc * 8;
  const ushort* gA1 = gA0 + (size_t)64 * K;
  const ushort* gB0 = W + (size_t)(bcol + srow) * K + kcsrc * 8;
  const ushort* gB1 = gB0 + (size_t)64 * K;

  auto stage = [&](int bf, int k0) {
    gload_lds16(gA0 + k0, &lA[bf][w * 512]);
    gload_lds16(gA1 + k0, &lA[bf][2048 + w * 512]);
    gload_lds16(gB0 + k0, &lB[bf][w * 512]);
    gload_lds16(gB1 + k0, &lB[bf][2048 + w * 512]);
  };

  const int l31 = lane & 31;
  const int lh = lane >> 5;   // 0/1

  f32x16 acc16[2][2];
  #pragma unroll
  for (int i = 0; i < 2; ++i)
    #pragma unroll
    for (int j = 0; j < 2; ++j)
      #pragma unroll
      for (int r = 0; r < 16; ++r) acc16[i][j][r] = 0.f;

  stage(0, 0);
  __syncthreads();

  int buf = 0;
  for (int k0 = 0; k0 < K; k0 += 32, buf ^= 1) {
    if (k0 + 32 < K) stage(buf ^ 1, k0 + 32);

    #pragma unroll
    for (int kh = 0; kh < 2; ++kh) {
      bf16x8 ar[2], br[2];
      #pragma unroll
      for (int mi = 0; mi < 2; ++mi) {
        int row = (wr << 6) + (mi << 5) + l31;
        int slot = (kh * 2 + lh) ^ ((row >> 1) & 3);
        ar[mi] = *(const bf16x8*)&lA[buf][(row << 5) + (slot << 3)];
      }
      #pragma unroll
      for (int ni = 0; ni < 2; ++ni) {
        int row = (wc << 6) + (ni << 5) + l31;
        int slot = (kh * 2 + lh) ^ ((row >> 1) & 3);
        br[ni] = *(const bf16x8*)&lB[buf][(row << 5) + (slot << 3)];
      }
      #pragma unroll
      for (int mi = 0; mi < 2; ++mi)
        #pragma unroll
        for (int ni = 0; ni < 2; ++ni)
          acc16[mi][ni] = __builtin_amdgcn_mfma_f32_32x32x16_bf16(
              ar[mi], br[ni], acc16[mi][ni], 0, 0, 0);
    }
    __syncthreads();
  }

  // ---- epilogue ----
  float* ldsS = (float*)&lA[0][0];   // EPI3: per-row sumsq (buffers dead now)
  if (EPI == 3) {
    if (tid < 128) ldsS[tid] = 0.f;
    __syncthreads();
  }

  #pragma unroll
  for (int mi = 0; mi < 2; ++mi) {
    const int rb0 = brow + (wr << 6) + (mi << 5) + (lh << 2);
    #pragma unroll
    for (int ni = 0; ni < 2; ++ni) {
      const int col = bcol + (wc << 6) + (ni << 5) + l31;
      if (EPI == 0) {
        if (col < 1024) {
          #pragma unroll
          for (int reg = 0; reg < 16; ++reg) {
            int row = rb0 + (reg & 3) + ((reg >> 2) << 3);
            float v = acc16[mi][ni][reg];
            ((ushort*)outp)[(size_t)row * 1024 + col] =
                f2bf(__expf(-0.5f * v * v));
          }
        } else {
          bool isk = col < 2048;
          int c = col - (isk ? 1024 : 2048);
          ushort* base = (isk ? kTp : vTp) +
                         ((size_t)((rb0 >> 12) * 16 + (c >> 6)) * 64 + (c & 63)) * 4096;
          #pragma unroll
          for (int q2 = 0; q2 < 4; ++q2) {
            int n0 = rb0 + (q2 << 3);          // 4 consecutive tokens n0..n0+3
            ushort4 o;
            #pragma unroll
            for (int j = 0; j < 4; ++j) {
              float v = acc16[mi][ni][q2 * 4 + j];
              if (isk) v = __expf(-0.5f * v * v);
              ((ushort*)&o)[j] = f2bf(v);
            }
            *(ushort4*)&base[n0 & 4095] = o;
          }
        }
      } else if (EPI == 1) {
        #pragma unroll
        for (int reg = 0; reg < 16; ++reg) {
          int row = rb0 + (reg & 3) + ((reg >> 2) << 3);
          size_t idx = (size_t)row * F + col;
          ((float*)outp)[idx] = resid[idx] + acc16[mi][ni][reg] + bias[col];
        }
      } else if (EPI == 2) {
        #pragma unroll
        for (int reg = 0; reg < 16; ++reg) {
          int row = rb0 + (reg & 3) + ((reg >> 2) << 3);
          float t2 = acc16[mi][ni][reg] * rowscale[row] + bias[col];
          float y = 0.79788456f * (t2 + 0.044715f * t2 * t2 * t2);
          float e = __expf(2.0f * y);
          float th = (e - 1.0f) / (e + 1.0f);
          ((ushort*)outp)[(size_t)row * F + col] = f2bf(0.5f * t2 * (1.0f + th));
        }
      }
    }
    if (EPI == 3) {
      // per (reg): 2 cols (ni) per lane; write out + xnraw, reduce x1^2 per row
      #pragma unroll
      for (int reg = 0; reg < 16; ++reg) {
        int row = rb0 + (reg & 3) + ((reg >> 2) << 3);
        float ss = 0.f;
        #pragma unroll
        for (int ni = 0; ni < 2; ++ni) {
          int col = bcol + (wc << 6) + (ni << 5) + l31;
          size_t idx = (size_t)row * F + col;
          float x1 = resid[idx] + acc16[mi][ni][reg] + bias[col];
          ((float*)outp)[idx] = x1;
          xnout[idx] = f2bf(x1 * escale[col]);
          ss += x1 * x1;
        }
        atomicAdd(&ldsS[row - brow], ss);
      }
    }
  }

  if (EPI == 3) {
    __syncthreads();
    if (tid < 128) atomicAdd(&sumsq[brow + tid], ldsS[tid]);
  }
}

// ---------------- kvT[b,h,e,d] = sum_n v[n,e]*k[n,d]  (MFMA, split-K) ----------------
__global__ __launch_bounds__(256)
void attn_kv_mfma(const ushort* __restrict__ kT, const ushort* __restrict__ vT,
                  float* __restrict__ kvT, float* __restrict__ ksum) {
  __shared__ float red[4][4096];
  int bi = blockIdx.x;
  int ksl = bi & 7, h = (bi >> 3) & 15, b = bi >> 7;
  int tid = threadIdx.x, lane = tid & 63, w = tid >> 6;
  int frow = lane & 15, kq = lane >> 4;
  const size_t bh = (size_t)(b * 16 + h) * 64;
  const ushort* vb = vT + bh * 4096;
  const ushort* kb = kT + bh * 4096;
  int tk0 = ksl * 512 + w * 128;

  f32x4 acc[4][4];
  #pragma unroll
  for (int i = 0; i < 4; ++i)
    #pragma unroll
    for (int j = 0; j < 4; ++j) acc[i][j] = (f32x4){0.f, 0.f, 0.f, 0.f};
  float kpart[4] = {0.f, 0.f, 0.f, 0.f};

  #pragma unroll
  for (int kstep = 0; kstep < 4; ++kstep) {
    int tok = tk0 + kstep * 32 + kq * 8;
    bf16x8 af[4], bfr[4];
    #pragma unroll
    for (int mi = 0; mi < 4; ++mi)
      af[mi] = *(const bf16x8*)&vb[(size_t)(mi * 16 + frow) * 4096 + tok];
    #pragma unroll
    for (int ni = 0; ni < 4; ++ni) {
      bfr[ni] = *(const bf16x8*)&kb[(size_t)(ni * 16 + frow) * 4096 + tok];
      #pragma unroll
      for (int j = 0; j < 8; ++j) kpart[ni] += bf2f((ushort)bfr[ni][j]);
    }
    #pragma unroll
    for (int mi = 0; mi < 4; ++mi)
      #pragma unroll
      for (int ni = 0; ni < 4; ++ni)
        acc[mi][ni] = __builtin_amdgcn_mfma_f32_16x16x32_bf16(
            af[mi], bfr[ni], acc[mi][ni], 0, 0, 0);
  }

  #pragma unroll
  for (int ni = 0; ni < 4; ++ni) {
    kpart[ni] += __shfl_xor(kpart[ni], 16);
    kpart[ni] += __shfl_xor(kpart[ni], 32);
  }
  if (lane < 16) {
    #pragma unroll
    for (int ni = 0; ni < 4; ++ni)
      atomicAdd(&ksum[(b * 16 + h) * 64 + ni * 16 + frow], kpart[ni]);
  }

  #pragma unroll
  for (int mi = 0; mi < 4; ++mi)
    #pragma unroll
    for (int ni = 0; ni < 4; ++ni)
      #pragma unroll
      for (int r = 0; r < 4; ++r)
        red[w][(mi * 16 + kq * 4 + r) * 64 + ni * 16 + frow] = acc[mi][ni][r];
  __syncthreads();
  float* kvg = kvT + (size_t)(b * 16 + h) * 4096;
  for (int i = tid; i < 4096; i += 256) {
    float s = red[0][i] + red[1][i] + red[2][i] + red[3][i];
    atomicAdd(&kvg[i], s);
  }
}

// ---------------- out[n,e] = z * sum_d q[n,d]*kvT[e,d]  (MFMA) ----------------
__global__ __launch_bounds__(256)
void attn_out_mfma(const ushort* __restrict__ qb, const float* __restrict__ kvT,
                   const float* __restrict__ ksum, ushort* __restrict__ ao) {
  __shared__ ushort skv[64 * 72];
  __shared__ float sks[64];
  int bi = blockIdx.x;
  int c = bi & 15, h = (bi >> 4) & 15, b = bi >> 8;
  int tid = threadIdx.x, lane = tid & 63, w = tid >> 6;
  int frow = lane & 15, kq = lane >> 4;
  const float* kvg = kvT + (size_t)(b * 16 + h) * 4096;
  for (int i = tid; i < 4096; i += 256)
    skv[(i >> 6) * 72 + (i & 63)] = f2bf(kvg[i]);
  if (tid < 64) sks[tid] = ksum[(b * 16 + h) * 64 + tid];
  __syncthreads();

  int m0 = b * 4096 + c * 256 + w * 64;
  f32x4 acc[4][4];
  #pragma unroll
  for (int i = 0; i < 4; ++i)
    #pragma unroll
    for (int j = 0; j < 4; ++j) acc[i][j] = (f32x4){0.f, 0.f, 0.f, 0.f};
  float dp[4] = {0.f, 0.f, 0.f, 0.f};

  #pragma unroll
  for (int kst = 0; kst < 2; ++kst) {
    int d0 = kst * 32 + kq * 8;
    bf16x8 af[4], bfr[4];
    #pragma unroll
    for (int mi = 0; mi < 4; ++mi)
      af[mi] = *(const bf16x8*)&qb[(size_t)(m0 + mi * 16 + frow) * 1024 + h * 64 + d0];
    #pragma unroll
    for (int ni = 0; ni < 4; ++ni)
      bfr[ni] = *(const bf16x8*)&skv[(ni * 16 + frow) * 72 + d0];
    #pragma unroll
    for (int mi = 0; mi < 4; ++mi) {
      float s = 0.f;
      #pragma unroll
      for (int j = 0; j < 8; ++j) s += bf2f((ushort)af[mi][j]) * sks[d0 + j];
      dp[mi] += s;
    }
    #pragma unroll
    for (int mi = 0; mi < 4; ++mi)
      #pragma unroll
      for (int ni = 0; ni < 4; ++ni)
        acc[mi][ni] = __builtin_amdgcn_mfma_f32_16x16x32_bf16(
            af[mi], bfr[ni], acc[mi][ni], 0, 0, 0);
  }

  #pragma unroll
  for (int mi = 0; mi < 4; ++mi) {
    dp[mi] += __shfl_xor(dp[mi], 16);
    dp[mi] += __shfl_xor(dp[mi], 32);
  }

  #pragma unroll
  for (int mi = 0; mi < 4; ++mi)
    #pragma unroll
    for (int ni = 0; ni < 4; ++ni)
      #pragma unroll
      for (int r = 0; r < 4; ++r) {
        float dotv = __shfl(dp[mi], (kq << 2) + r);
        float z = 1.f / (dotv + 1e-6f);
        int mrow = m0 + mi * 16 + kq * 4 + r;
        ao[(size_t)mrow * 1024 + h * 64 + ni * 16 + frow] =
            f2bf(acc[mi][ni][r] * z);
      }
}

extern "C" void kernel_launch(void* const* d_in, const int* in_sizes, int n_in,
                              void* d_out, int out_size, void* d_ws, size_t ws_size,
                              hipStream_t stream) {
  const float* x       = (const float*)d_in[0];
  const float* scale1  = (const float*)d_in[1];
  const float* scale2  = (const float*)d_in[2];
  const float* gamma   = (const float*)d_in[3];
  const float* qkv_w   = (const float*)d_in[4];
  const float* proj_w  = (const float*)d_in[5];
  const float* proj_b  = (const float*)d_in[6];
  const float* conv1_w = (const float*)d_in[7];
  const float* conv1_b = (const float*)d_in[8];
  const float* conv2_w = (const float*)d_in[9];
  const float* conv2_b = (const float*)d_in[10];
  float* out = (float*)d_out;

  char* ws = (char*)d_ws;
  size_t off = 0;
  auto alloc = [&](size_t bytes) {
    void* p = ws + off;
    off += (bytes + 255) & ~(size_t)255;
    return p;
  };
  ushort* xn     = (ushort*)alloc((size_t)MTOK * 1024 * 2);
  ushort* qb     = (ushort*)alloc((size_t)MTOK * 1024 * 2);
  ushort* kT     = (ushort*)alloc((size_t)MTOK * 1024 * 2);  // [b,h,d,n]
  ushort* vT     = (ushort*)alloc((size_t)MTOK * 1024 * 2);  // [b,h,e,n]
  ushort* attn_o = (ushort*)alloc((size_t)MTOK * 1024 * 2);
  float*  kvT    = (float*)alloc((size_t)(4 * 16 * 64 * 64 + 4 * 16 * 64) * 4);
  float*  ksum   = kvT + 4 * 16 * 64 * 64;
  ushort* wq = (ushort*)alloc((size_t)3072 * 1024 * 2);
  ushort* wp = (ushort*)alloc((size_t)1024 * 1024 * 2);
  ushort* w1 = (ushort*)alloc((size_t)2048 * 1024 * 2);
  ushort* w2 = (ushort*)alloc((size_t)1024 * 2048 * 2);
  float*  gbp = (float*)alloc(1024 * 4);     // gamma*proj_b
  float*  gbc = (float*)alloc(1024 * 4);     // gamma*conv2_b
  float*  sumsq = (float*)alloc(MTOK * 4);   // per-row sum(x1^2)
  float*  rnb   = (float*)alloc(MTOK * 4);   // rn per row
  ushort* hid = kT;   // [MTOK][2048] bf16 reuses kT+vT (dead after attention)
  if (off > ws_size) return;

  hipMemsetAsync(kvT, 0, (size_t)(4 * 16 * 64 * 64 + 4 * 16 * 64) * 4, stream);
  hipMemsetAsync(sumsq, 0, MTOK * 4, stream);
  f32_to_bf16_k<<<3072, 256, 0, stream>>>(qkv_w, wq, 786432);
  f32_to_bf16_rs_k<<<1024, 256, 0, stream>>>(proj_w, wp, 262144, gamma, 1024);
  f32_to_bf16_k<<<2048, 256, 0, stream>>>(conv1_w, w1, 524288);
  f32_to_bf16_rs_k<<<2048, 256, 0, stream>>>(conv2_w, w2, 524288, gamma, 2048);
  gbias_k<<<4, 256, 0, stream>>>(gamma, proj_b, gbp, 1024);
  gbias_k<<<4, 256, 0, stream>>>(gamma, conv2_b, gbc, 1024);

  // attention branch
  rmsnorm_k<<<MTOK, 256, 0, stream>>>(x, scale1, xn);
  gemm_bt<0><<<128 * 24, 256, 0, stream>>>(xn, wq, qb, nullptr, nullptr,
                                           kT, vT, nullptr, nullptr, nullptr, nullptr,
                                           MTOK, 3072, 1024);
  attn_kv_mfma<<<512, 256, 0, stream>>>(kT, vT, kvT, ksum);
  attn_out_mfma<<<1024, 256, 0, stream>>>(qb, kvT, ksum, attn_o);
  // proj + residual + fused norm-stats + xnraw (x1*scale2 bf16)
  gemm_bt<3><<<128 * 8, 256, 0, stream>>>(attn_o, wp, out, gbp, x,
                                          nullptr, nullptr, scale2, nullptr,
                                          sumsq, xn, MTOK, 1024, 1024);
  rn_k<<<64, 256, 0, stream>>>(sumsq, rnb, MTOK);

  // MLP branch (rn applied in conv1 epilogue; x1 lives in d_out)
  gemm_bt<2><<<128 * 16, 256, 0, stream>>>(xn, w1, hid, conv1_b, nullptr,
                                           nullptr, nullptr, nullptr, rnb,
                                           nullptr, nullptr, MTOK, 2048, 1024);
  gemm_bt<1><<<128 * 8, 256, 0, stream>>>(hid, w2, out, gbc, out,
                                          nullptr, nullptr, nullptr, nullptr,
                                          nullptr, nullptr, MTOK, 1024, 2048);
}

// Round 9
// 472.192 us; speedup vs baseline: 1.1111x; 1.1111x over previous
//
#include <hip/hip_runtime.h>
#include <hip/hip_bf16.h>
#include <math.h>

#define MTOK 16384   // B*N = 4*4096

typedef __attribute__((ext_vector_type(8))) short bf16x8;
typedef __attribute__((ext_vector_type(4))) float f32x4;

__device__ __forceinline__ float bf2f(ushort u) {
  union { unsigned int u; float f; } c; c.u = ((unsigned int)u) << 16; return c.f;
}
__device__ __forceinline__ ushort f2bf(float f) {
  union { float f; unsigned int u; } c; c.f = f;
  unsigned int r = c.u + 0x7fffu + ((c.u >> 16) & 1u);
  return (ushort)(r >> 16);
}

__device__ __forceinline__ void gload_lds16(const void* g, void* l) {
  __builtin_amdgcn_global_load_lds(
      (const __attribute__((address_space(1))) unsigned int*)g,
      (__attribute__((address_space(3))) unsigned int*)l, 16, 0, 0);
}

// ---------------- fp32 -> bf16 convert (weights) ----------------
__global__ __launch_bounds__(256)
void f32_to_bf16_k(const float* __restrict__ in, ushort* __restrict__ out, int n4) {
  int i = blockIdx.x * 256 + threadIdx.x;
  if (i >= n4) return;
  float4 v = *(const float4*)&in[(size_t)i * 4];
  ushort4 o;
  o.x = f2bf(v.x); o.y = f2bf(v.y); o.z = f2bf(v.z); o.w = f2bf(v.w);
  *(ushort4*)&out[(size_t)i * 4] = o;
}

// fp32 -> bf16 with per-ROW scale (folds gamma into weight rows): row = idx/K_in
__global__ __launch_bounds__(256)
void f32_to_bf16_rs_k(const float* __restrict__ in, ushort* __restrict__ out,
                      int n4, const float* __restrict__ rs, int K_in) {
  int i = blockIdx.x * 256 + threadIdx.x;
  if (i >= n4) return;
  float g = rs[(i * 4) / K_in];
  float4 v = *(const float4*)&in[(size_t)i * 4];
  ushort4 o;
  o.x = f2bf(v.x * g); o.y = f2bf(v.y * g); o.z = f2bf(v.z * g); o.w = f2bf(v.w * g);
  *(ushort4*)&out[(size_t)i * 4] = o;
}

// gb[c] = gamma[c] * bias[c]
__global__ __launch_bounds__(256)
void gbias_k(const float* __restrict__ gamma, const float* __restrict__ bias,
             float* __restrict__ gb, int n) {
  int i = blockIdx.x * 256 + threadIdx.x;
  if (i < n) gb[i] = gamma[i] * bias[i];
}

// rn[i] = (sqrt(1024)+eps)/sqrt(sumsq[i])
__global__ __launch_bounds__(256)
void rn_k(const float* __restrict__ sumsq, float* __restrict__ rn, int n) {
  int i = blockIdx.x * 256 + threadIdx.x;
  if (i < n) rn[i] = (32.0f + 1e-6f) / sqrtf(sumsq[i]);
}

// ---------------- RMSNorm: fp32 in -> bf16 out (branch 1 only) ----------------
__global__ __launch_bounds__(256)
void rmsnorm_k(const float* __restrict__ x, const float* __restrict__ scale,
               ushort* __restrict__ out) {
  __shared__ float red[4];
  int row = blockIdx.x;
  int t = threadIdx.x;
  const float* xr = x + (size_t)row * 1024;
  float4 v = *(const float4*)&xr[t * 4];
  float s = v.x*v.x + v.y*v.y + v.z*v.z + v.w*v.w;
  #pragma unroll
  for (int off = 32; off > 0; off >>= 1) s += __shfl_xor(s, off);
  if ((t & 63) == 0) red[t >> 6] = s;
  __syncthreads();
  float tot = red[0] + red[1] + red[2] + red[3];
  float rn = (32.0f + 1e-6f) / sqrtf(tot);
  float4 sc = *(const float4*)&scale[t * 4];
  ushort4 o;
  o.x = f2bf(v.x * rn * sc.x);
  o.y = f2bf(v.y * rn * sc.y);
  o.z = f2bf(v.z * rn * sc.z);
  o.w = f2bf(v.w * rn * sc.w);
  *(ushort4*)&out[(size_t)row * 1024 + t * 4] = o;
}

// ---------------- bf16 MFMA GEMM: out[M,F] = A[M,K] @ W[F,K]^T ----------------
// R6-proven core: 128x128 tile, BK=32, 4 waves, 16x16x32 MFMA, 2-phase LDS dbuf,
// kc-chunk XOR swizzle on global SOURCE + ds_read (both-sides), T1 XCD chunking.
// EPI 0: qkv — q(phi) token-major; k(phi)/v transposed [b,h,ch,n]
// EPI 1: outf32 = resid + acc + gb[col]                      (conv2 final)
// EPI 2: gelu(acc*rowscale[row] + bias) bf16, tanh approx    (conv1, rn deferred)
// EPI 3: proj + norm-fusion: x1=resid+acc+gb -> out f32; xnout=bf16(x1*escale);
//        per-row sum(x1^2) -> LDS atomic -> global atomic    (kills rmsnorm#2)
template<int EPI>
__global__ __launch_bounds__(256, 2)
void gemm_bt(const ushort* __restrict__ A, const ushort* __restrict__ W,
             void* __restrict__ outp, const float* __restrict__ bias,
             const float* __restrict__ resid,
             ushort* __restrict__ kTp, ushort* __restrict__ vTp,
             const float* __restrict__ escale, const float* __restrict__ rowscale,
             float* __restrict__ sumsq, ushort* __restrict__ xnout,
             int M, int F, int K) {
  __shared__ ushort lA[2][128 * 32];
  __shared__ ushort lB[2][128 * 32];
  const int tid = threadIdx.x;
  const int lane = tid & 63;
  const int w = tid >> 6;
  const int nBn = F >> 7;
  // T1: XCD gets a contiguous bm-major chunk (bijective: grid%8==0)
  const int cpx = (int)gridDim.x >> 3;
  const int tile = ((int)blockIdx.x & 7) * cpx + ((int)blockIdx.x >> 3);
  const int bm = tile / nBn;
  const int bn = tile % nBn;
  const int brow = bm << 7, bcol = bn << 7;
  const int wr = w >> 1, wc = w & 1;

  const int srow = (w << 4) + (lane >> 2);
  const int key = (srow >> 1) & 3;
  const int kcsrc = (lane & 3) ^ key;
  const ushort* gA0 = A + (size_t)(brow + srow) * K + kcsrc * 8;
  const ushort* gA1 = gA0 + (size_t)64 * K;
  const ushort* gB0 = W + (size_t)(bcol + srow) * K + kcsrc * 8;
  const ushort* gB1 = gB0 + (size_t)64 * K;

  auto stage = [&](int bf, int k0) {
    gload_lds16(gA0 + k0, &lA[bf][w * 512]);
    gload_lds16(gA1 + k0, &lA[bf][2048 + w * 512]);
    gload_lds16(gB0 + k0, &lB[bf][w * 512]);
    gload_lds16(gB1 + k0, &lB[bf][2048 + w * 512]);
  };

  const int frow = lane & 15;
  const int kq = lane >> 4;

  f32x4 acc[4][4];
  #pragma unroll
  for (int i = 0; i < 4; ++i)
    #pragma unroll
    for (int j = 0; j < 4; ++j) acc[i][j] = (f32x4){0.f, 0.f, 0.f, 0.f};

  stage(0, 0);
  __syncthreads();

  int buf = 0;
  for (int k0 = 0; k0 < K; k0 += 32, buf ^= 1) {
    if (k0 + 32 < K) stage(buf ^ 1, k0 + 32);

    bf16x8 af[4], bfr[4];
    #pragma unroll
    for (int mi = 0; mi < 4; ++mi) {
      int row = (wr << 6) + (mi << 4) + frow;
      int off = (row << 5) + ((kq ^ ((row >> 1) & 3)) << 3);
      af[mi] = *(const bf16x8*)&lA[buf][off];
    }
    #pragma unroll
    for (int ni = 0; ni < 4; ++ni) {
      int row = (wc << 6) + (ni << 4) + frow;
      int off = (row << 5) + ((kq ^ ((row >> 1) & 3)) << 3);
      bfr[ni] = *(const bf16x8*)&lB[buf][off];
    }
    #pragma unroll
    for (int mi = 0; mi < 4; ++mi)
      #pragma unroll
      for (int ni = 0; ni < 4; ++ni)
        acc[mi][ni] = __builtin_amdgcn_mfma_f32_16x16x32_bf16(
            af[mi], bfr[ni], acc[mi][ni], 0, 0, 0);
    __syncthreads();
  }

  // ---- epilogue: C row = rbase + r, col = bcol + wc*64 + ni*16 + frow ----
  float* ldsS = (float*)&lA[0][0];   // EPI3: per-row sumsq (LDS buffers dead now)
  if (EPI == 3) {
    if (tid < 128) ldsS[tid] = 0.f;
    __syncthreads();
  }

  #pragma unroll
  for (int mi = 0; mi < 4; ++mi) {
    const int rbase = brow + (wr << 6) + (mi << 4) + (kq << 2);
    float ss[4] = {0.f, 0.f, 0.f, 0.f};
    #pragma unroll
    for (int ni = 0; ni < 4; ++ni) {
      int col = bcol + (wc << 6) + (ni << 4) + frow;
      if (EPI == 0) {
        if (col < 1024) {
          #pragma unroll
          for (int r = 0; r < 4; ++r) {
            float v = acc[mi][ni][r];
            ((ushort*)outp)[(size_t)(rbase + r) * 1024 + col] =
                f2bf(__expf(-0.5f * v * v));
          }
        } else {
          bool isk = col < 2048;
          int c = col - (isk ? 1024 : 2048);
          int b = rbase >> 12, n = rbase & 4095;
          ushort4 o;
          #pragma unroll
          for (int r = 0; r < 4; ++r) {
            float v = acc[mi][ni][r];
            if (isk) v = __expf(-0.5f * v * v);
            ((ushort*)&o)[r] = f2bf(v);
          }
          ushort* dst = (isk ? kTp : vTp) +
                        ((size_t)(b * 16 + (c >> 6)) * 64 + (c & 63)) * 4096 + n;
          *(ushort4*)dst = o;
        }
      } else if (EPI == 1) {
        #pragma unroll
        for (int r = 0; r < 4; ++r) {
          size_t idx = (size_t)(rbase + r) * F + col;
          ((float*)outp)[idx] = resid[idx] + acc[mi][ni][r] + bias[col];
        }
      } else if (EPI == 2) {
        #pragma unroll
        for (int r = 0; r < 4; ++r) {
          float t2 = acc[mi][ni][r] * rowscale[rbase + r] + bias[col];
          float y = 0.79788456f * (t2 + 0.044715f * t2 * t2 * t2);
          float e = __expf(2.0f * y);
          float th = (e - 1.0f) / (e + 1.0f);
          ((ushort*)outp)[(size_t)(rbase + r) * F + col] =
              f2bf(0.5f * t2 * (1.0f + th));
        }
      } else {  // EPI 3
        #pragma unroll
        for (int r = 0; r < 4; ++r) {
          size_t idx = (size_t)(rbase + r) * F + col;
          float x1 = resid[idx] + acc[mi][ni][r] + bias[col];
          ((float*)outp)[idx] = x1;
          xnout[idx] = f2bf(x1 * escale[col]);
          ss[r] += x1 * x1;
        }
      }
    }
    if (EPI == 3) {
      #pragma unroll
      for (int r = 0; r < 4; ++r)
        atomicAdd(&ldsS[rbase - brow + r], ss[r]);
    }
  }

  if (EPI == 3) {
    __syncthreads();
    if (tid < 128) atomicAdd(&sumsq[brow + tid], ldsS[tid]);
  }
}

// ---------------- kvT[b,h,e,d] = sum_n v[n,e]*k[n,d]  (MFMA, split-K) ----------------
__global__ __launch_bounds__(256)
void attn_kv_mfma(const ushort* __restrict__ kT, const ushort* __restrict__ vT,
                  float* __restrict__ kvT, float* __restrict__ ksum) {
  __shared__ float red[4][4096];
  int bi = blockIdx.x;
  int ksl = bi & 7, h = (bi >> 3) & 15, b = bi >> 7;
  int tid = threadIdx.x, lane = tid & 63, w = tid >> 6;
  int frow = lane & 15, kq = lane >> 4;
  const size_t bh = (size_t)(b * 16 + h) * 64;
  const ushort* vb = vT + bh * 4096;
  const ushort* kb = kT + bh * 4096;
  int tk0 = ksl * 512 + w * 128;

  f32x4 acc[4][4];
  #pragma unroll
  for (int i = 0; i < 4; ++i)
    #pragma unroll
    for (int j = 0; j < 4; ++j) acc[i][j] = (f32x4){0.f, 0.f, 0.f, 0.f};
  float kpart[4] = {0.f, 0.f, 0.f, 0.f};

  #pragma unroll
  for (int kstep = 0; kstep < 4; ++kstep) {
    int tok = tk0 + kstep * 32 + kq * 8;
    bf16x8 af[4], bfr[4];
    #pragma unroll
    for (int mi = 0; mi < 4; ++mi)
      af[mi] = *(const bf16x8*)&vb[(size_t)(mi * 16 + frow) * 4096 + tok];
    #pragma unroll
    for (int ni = 0; ni < 4; ++ni) {
      bfr[ni] = *(const bf16x8*)&kb[(size_t)(ni * 16 + frow) * 4096 + tok];
      #pragma unroll
      for (int j = 0; j < 8; ++j) kpart[ni] += bf2f((ushort)bfr[ni][j]);
    }
    #pragma unroll
    for (int mi = 0; mi < 4; ++mi)
      #pragma unroll
      for (int ni = 0; ni < 4; ++ni)
        acc[mi][ni] = __builtin_amdgcn_mfma_f32_16x16x32_bf16(
            af[mi], bfr[ni], acc[mi][ni], 0, 0, 0);
  }

  #pragma unroll
  for (int ni = 0; ni < 4; ++ni) {
    kpart[ni] += __shfl_xor(kpart[ni], 16);
    kpart[ni] += __shfl_xor(kpart[ni], 32);
  }
  if (lane < 16) {
    #pragma unroll
    for (int ni = 0; ni < 4; ++ni)
      atomicAdd(&ksum[(b * 16 + h) * 64 + ni * 16 + frow], kpart[ni]);
  }

  #pragma unroll
  for (int mi = 0; mi < 4; ++mi)
    #pragma unroll
    for (int ni = 0; ni < 4; ++ni)
      #pragma unroll
      for (int r = 0; r < 4; ++r)
        red[w][(mi * 16 + kq * 4 + r) * 64 + ni * 16 + frow] = acc[mi][ni][r];
  __syncthreads();
  float* kvg = kvT + (size_t)(b * 16 + h) * 4096;
  for (int i = tid; i < 4096; i += 256) {
    float s = red[0][i] + red[1][i] + red[2][i] + red[3][i];
    atomicAdd(&kvg[i], s);
  }
}

// ---------------- out[n,e] = z * sum_d q[n,d]*kvT[e,d]  (MFMA) ----------------
__global__ __launch_bounds__(256)
void attn_out_mfma(const ushort* __restrict__ qb, const float* __restrict__ kvT,
                   const float* __restrict__ ksum, ushort* __restrict__ ao) {
  __shared__ ushort skv[64 * 72];
  __shared__ float sks[64];
  int bi = blockIdx.x;
  int c = bi & 15, h = (bi >> 4) & 15, b = bi >> 8;
  int tid = threadIdx.x, lane = tid & 63, w = tid >> 6;
  int frow = lane & 15, kq = lane >> 4;
  const float* kvg = kvT + (size_t)(b * 16 + h) * 4096;
  for (int i = tid; i < 4096; i += 256)
    skv[(i >> 6) * 72 + (i & 63)] = f2bf(kvg[i]);
  if (tid < 64) sks[tid] = ksum[(b * 16 + h) * 64 + tid];
  __syncthreads();

  int m0 = b * 4096 + c * 256 + w * 64;
  f32x4 acc[4][4];
  #pragma unroll
  for (int i = 0; i < 4; ++i)
    #pragma unroll
    for (int j = 0; j < 4; ++j) acc[i][j] = (f32x4){0.f, 0.f, 0.f, 0.f};
  float dp[4] = {0.f, 0.f, 0.f, 0.f};

  #pragma unroll
  for (int kst = 0; kst < 2; ++kst) {
    int d0 = kst * 32 + kq * 8;
    bf16x8 af[4], bfr[4];
    #pragma unroll
    for (int mi = 0; mi < 4; ++mi)
      af[mi] = *(const bf16x8*)&qb[(size_t)(m0 + mi * 16 + frow) * 1024 + h * 64 + d0];
    #pragma unroll
    for (int ni = 0; ni < 4; ++ni)
      bfr[ni] = *(const bf16x8*)&skv[(ni * 16 + frow) * 72 + d0];
    #pragma unroll
    for (int mi = 0; mi < 4; ++mi) {
      float s = 0.f;
      #pragma unroll
      for (int j = 0; j < 8; ++j) s += bf2f((ushort)af[mi][j]) * sks[d0 + j];
      dp[mi] += s;
    }
    #pragma unroll
    for (int mi = 0; mi < 4; ++mi)
      #pragma unroll
      for (int ni = 0; ni < 4; ++ni)
        acc[mi][ni] = __builtin_amdgcn_mfma_f32_16x16x32_bf16(
            af[mi], bfr[ni], acc[mi][ni], 0, 0, 0);
  }

  #pragma unroll
  for (int mi = 0; mi < 4; ++mi) {
    dp[mi] += __shfl_xor(dp[mi], 16);
    dp[mi] += __shfl_xor(dp[mi], 32);
  }

  #pragma unroll
  for (int mi = 0; mi < 4; ++mi)
    #pragma unroll
    for (int ni = 0; ni < 4; ++ni)
      #pragma unroll
      for (int r = 0; r < 4; ++r) {
        float dotv = __shfl(dp[mi], (kq << 2) + r);
        float z = 1.f / (dotv + 1e-6f);
        int mrow = m0 + mi * 16 + kq * 4 + r;
        ao[(size_t)mrow * 1024 + h * 64 + ni * 16 + frow] =
            f2bf(acc[mi][ni][r] * z);
      }
}

extern "C" void kernel_launch(void* const* d_in, const int* in_sizes, int n_in,
                              void* d_out, int out_size, void* d_ws, size_t ws_size,
                              hipStream_t stream) {
  const float* x       = (const float*)d_in[0];
  const float* scale1  = (const float*)d_in[1];
  const float* scale2  = (const float*)d_in[2];
  const float* gamma   = (const float*)d_in[3];
  const float* qkv_w   = (const float*)d_in[4];
  const float* proj_w  = (const float*)d_in[5];
  const float* proj_b  = (const float*)d_in[6];
  const float* conv1_w = (const float*)d_in[7];
  const float* conv1_b = (const float*)d_in[8];
  const float* conv2_w = (const float*)d_in[9];
  const float* conv2_b = (const float*)d_in[10];
  float* out = (float*)d_out;

  char* ws = (char*)d_ws;
  size_t off = 0;
  auto alloc = [&](size_t bytes) {
    void* p = ws + off;
    off += (bytes + 255) & ~(size_t)255;
    return p;
  };
  ushort* xn     = (ushort*)alloc((size_t)MTOK * 1024 * 2);
  ushort* qb     = (ushort*)alloc((size_t)MTOK * 1024 * 2);
  ushort* kT     = (ushort*)alloc((size_t)MTOK * 1024 * 2);  // [b,h,d,n]
  ushort* vT     = (ushort*)alloc((size_t)MTOK * 1024 * 2);  // [b,h,e,n]
  ushort* attn_o = (ushort*)alloc((size_t)MTOK * 1024 * 2);
  float*  kvT    = (float*)alloc((size_t)(4 * 16 * 64 * 64 + 4 * 16 * 64) * 4);
  float*  ksum   = kvT + 4 * 16 * 64 * 64;
  ushort* wq = (ushort*)alloc((size_t)3072 * 1024 * 2);
  ushort* wp = (ushort*)alloc((size_t)1024 * 1024 * 2);
  ushort* w1 = (ushort*)alloc((size_t)2048 * 1024 * 2);
  ushort* w2 = (ushort*)alloc((size_t)1024 * 2048 * 2);
  float*  gbp = (float*)alloc(1024 * 4);     // gamma*proj_b
  float*  gbc = (float*)alloc(1024 * 4);     // gamma*conv2_b
  float*  sumsq = (float*)alloc(MTOK * 4);   // per-row sum(x1^2)
  float*  rnb   = (float*)alloc(MTOK * 4);   // rn per row
  ushort* hid = kT;   // [MTOK][2048] bf16 reuses kT+vT (dead after attention)
  if (off > ws_size) return;

  hipMemsetAsync(kvT, 0, (size_t)(4 * 16 * 64 * 64 + 4 * 16 * 64) * 4, stream);
  hipMemsetAsync(sumsq, 0, MTOK * 4, stream);
  f32_to_bf16_k<<<3072, 256, 0, stream>>>(qkv_w, wq, 786432);
  f32_to_bf16_rs_k<<<1024, 256, 0, stream>>>(proj_w, wp, 262144, gamma, 1024);
  f32_to_bf16_k<<<2048, 256, 0, stream>>>(conv1_w, w1, 524288);
  f32_to_bf16_rs_k<<<2048, 256, 0, stream>>>(conv2_w, w2, 524288, gamma, 2048);
  gbias_k<<<4, 256, 0, stream>>>(gamma, proj_b, gbp, 1024);
  gbias_k<<<4, 256, 0, stream>>>(gamma, conv2_b, gbc, 1024);

  // attention branch
  rmsnorm_k<<<MTOK, 256, 0, stream>>>(x, scale1, xn);
  gemm_bt<0><<<128 * 24, 256, 0, stream>>>(xn, wq, qb, nullptr, nullptr,
                                           kT, vT, nullptr, nullptr, nullptr, nullptr,
                                           MTOK, 3072, 1024);
  attn_kv_mfma<<<512, 256, 0, stream>>>(kT, vT, kvT, ksum);
  attn_out_mfma<<<1024, 256, 0, stream>>>(qb, kvT, ksum, attn_o);
  // proj + residual + fused norm-stats + xnraw (x1*scale2 bf16)
  gemm_bt<3><<<128 * 8, 256, 0, stream>>>(attn_o, wp, out, gbp, x,
                                          nullptr, nullptr, scale2, nullptr,
                                          sumsq, xn, MTOK, 1024, 1024);
  rn_k<<<64, 256, 0, stream>>>(sumsq, rnb, MTOK);

  // MLP branch (rn applied in conv1 epilogue; x1 lives in d_out)
  gemm_bt<2><<<128 * 16, 256, 0, stream>>>(xn, w1, hid, conv1_b, nullptr,
                                           nullptr, nullptr, nullptr, rnb,
                                           nullptr, nullptr, MTOK, 2048, 1024);
  gemm_bt<1><<<128 * 8, 256, 0, stream>>>(hid, w2, out, gbc, out,
                                          nullptr, nullptr, nullptr, nullptr,
                                          nullptr, nullptr, MTOK, 1024, 2048);
}

// Round 10
// 448.469 us; speedup vs baseline: 1.1699x; 1.0529x over previous
//
#include <hip/hip_runtime.h>
#include <hip/hip_bf16.h>
#include <math.h>

#define MTOK 16384   // B*N = 4*4096

typedef __attribute__((ext_vector_type(8))) short bf16x8;
typedef __attribute__((ext_vector_type(4))) float f32x4;

__device__ __forceinline__ float bf2f(ushort u) {
  union { unsigned int u; float f; } c; c.u = ((unsigned int)u) << 16; return c.f;
}
__device__ __forceinline__ ushort f2bf(float f) {
  __hip_bfloat16 h = __float2bfloat16(f);   // RNE; compiler can pack to cvt_pk
  return *(ushort*)&h;
}

__device__ __forceinline__ void gload_lds16(const void* g, void* l) {
  __builtin_amdgcn_global_load_lds(
      (const __attribute__((address_space(1))) unsigned int*)g,
      (__attribute__((address_space(3))) unsigned int*)l, 16, 0, 0);
}

// ---------------- fused prep: weight converts + gamma-folds + zeroing ----------------
// blocks [0,3072): qkv_w->wq | [3072,4096): proj_w*gamma->wp | [4096,6144): conv1_w->w1
// [6144,8192): conv2_w*gamma->w2 | [8192,8200): gbp/gbc | [8200,8460): zero kvT+ksum
// [8460,8476): zero sumsq
__global__ __launch_bounds__(256)
void prep_k(const float* __restrict__ qkv_w, ushort* __restrict__ wq,
            const float* __restrict__ proj_w, ushort* __restrict__ wp,
            const float* __restrict__ conv1_w, ushort* __restrict__ w1,
            const float* __restrict__ conv2_w, ushort* __restrict__ w2,
            const float* __restrict__ gamma,
            const float* __restrict__ proj_b, const float* __restrict__ conv2_b,
            float* __restrict__ gbp, float* __restrict__ gbc,
            float* __restrict__ zero1, float* __restrict__ sumsq) {
  int b = blockIdx.x, t = threadIdx.x;
  if (b < 3072) {
    int i = b * 256 + t;
    float4 v = *(const float4*)&qkv_w[(size_t)i * 4];
    ushort4 o = {f2bf(v.x), f2bf(v.y), f2bf(v.z), f2bf(v.w)};
    *(ushort4*)&wq[(size_t)i * 4] = o;
  } else if (b < 4096) {
    int i = (b - 3072) * 256 + t;
    float g = gamma[(i * 4) >> 10];
    float4 v = *(const float4*)&proj_w[(size_t)i * 4];
    ushort4 o = {f2bf(v.x * g), f2bf(v.y * g), f2bf(v.z * g), f2bf(v.w * g)};
    *(ushort4*)&wp[(size_t)i * 4] = o;
  } else if (b < 6144) {
    int i = (b - 4096) * 256 + t;
    float4 v = *(const float4*)&conv1_w[(size_t)i * 4];
    ushort4 o = {f2bf(v.x), f2bf(v.y), f2bf(v.z), f2bf(v.w)};
    *(ushort4*)&w1[(size_t)i * 4] = o;
  } else if (b < 8192) {
    int i = (b - 6144) * 256 + t;
    float g = gamma[(i * 4) >> 11];
    float4 v = *(const float4*)&conv2_w[(size_t)i * 4];
    ushort4 o = {f2bf(v.x * g), f2bf(v.y * g), f2bf(v.z * g), f2bf(v.w * g)};
    *(ushort4*)&w2[(size_t)i * 4] = o;
  } else if (b < 8200) {
    int i = (b - 8192) * 256 + t;
    if (i < 1024) gbp[i] = gamma[i] * proj_b[i];
    else if (i < 2048) gbc[i - 1024] = gamma[i - 1024] * conv2_b[i - 1024];
  } else if (b < 8460) {
    int i = (b - 8200) * 256 + t;     // 66560 float4 = 266240 floats (kvT+ksum)
    if (i < 66560) ((float4*)zero1)[i] = (float4){0.f, 0.f, 0.f, 0.f};
  } else {
    int i = (b - 8460) * 256 + t;     // 4096 float4 = 16384 floats (sumsq)
    if (i < 4096) ((float4*)sumsq)[i] = (float4){0.f, 0.f, 0.f, 0.f};
  }
}

// rn[i] = (sqrt(1024)+eps)/sqrt(sumsq[i])
__global__ __launch_bounds__(256)
void rn_k(const float* __restrict__ sumsq, float* __restrict__ rn, int n) {
  int i = blockIdx.x * 256 + threadIdx.x;
  if (i < n) rn[i] = (32.0f + 1e-6f) / sqrtf(sumsq[i]);
}

// ---------------- RMSNorm: fp32 in -> bf16 out (branch 1 only) ----------------
__global__ __launch_bounds__(256)
void rmsnorm_k(const float* __restrict__ x, const float* __restrict__ scale,
               ushort* __restrict__ out) {
  __shared__ float red[4];
  int row = blockIdx.x;
  int t = threadIdx.x;
  const float* xr = x + (size_t)row * 1024;
  float4 v = *(const float4*)&xr[t * 4];
  float s = v.x*v.x + v.y*v.y + v.z*v.z + v.w*v.w;
  #pragma unroll
  for (int off = 32; off > 0; off >>= 1) s += __shfl_xor(s, off);
  if ((t & 63) == 0) red[t >> 6] = s;
  __syncthreads();
  float tot = red[0] + red[1] + red[2] + red[3];
  float rn = (32.0f + 1e-6f) / sqrtf(tot);
  float4 sc = *(const float4*)&scale[t * 4];
  ushort4 o;
  o.x = f2bf(v.x * rn * sc.x);
  o.y = f2bf(v.y * rn * sc.y);
  o.z = f2bf(v.z * rn * sc.z);
  o.w = f2bf(v.w * rn * sc.w);
  *(ushort4*)&out[(size_t)row * 1024 + t * 4] = o;
}

// ---------------- bf16 MFMA GEMM: out[M,F] = A[M,K] @ W[F,K]^T ----------------
// R6-proven core: 128x128 tile, BK=32, 4 waves, 16x16x32 MFMA, 2-phase LDS dbuf,
// kc-chunk XOR swizzle on global SOURCE + ds_read (both-sides), T1 XCD chunking.
// EPI 0: qkv — q(phi) token-major; k(phi)/v transposed [b,h,ch,n]
// EPI 1: outf32 = resid + acc + gb[col]                      (conv2 final)
// EPI 2: gelu(acc*rowscale[row] + bias) bf16, tanh approx    (conv1, rn deferred)
// EPI 3: proj + norm-fusion: x1=resid+acc+gb -> out f32; xnout=bf16(x1*escale);
//        per-row sum(x1^2): shfl-reduce over frow -> 1 global atomic per group
template<int EPI>
__global__ __launch_bounds__(256, 2)
void gemm_bt(const ushort* __restrict__ A, const ushort* __restrict__ W,
             void* __restrict__ outp, const float* __restrict__ bias,
             const float* __restrict__ resid,
             ushort* __restrict__ kTp, ushort* __restrict__ vTp,
             const float* __restrict__ escale, const float* __restrict__ rowscale,
             float* __restrict__ sumsq, ushort* __restrict__ xnout,
             int M, int F, int K) {
  __shared__ ushort lA[2][128 * 32];
  __shared__ ushort lB[2][128 * 32];
  const int tid = threadIdx.x;
  const int lane = tid & 63;
  const int w = tid >> 6;
  const int nBn = F >> 7;
  // T1: XCD gets a contiguous bm-major chunk (bijective: grid%8==0)
  const int cpx = (int)gridDim.x >> 3;
  const int tile = ((int)blockIdx.x & 7) * cpx + ((int)blockIdx.x >> 3);
  const int bm = tile / nBn;
  const int bn = tile % nBn;
  const int brow = bm << 7, bcol = bn << 7;
  const int wr = w >> 1, wc = w & 1;

  const int srow = (w << 4) + (lane >> 2);
  const int key = (srow >> 1) & 3;
  const int kcsrc = (lane & 3) ^ key;
  const ushort* gA0 = A + (size_t)(brow + srow) * K + kcsrc * 8;
  const ushort* gA1 = gA0 + (size_t)64 * K;
  const ushort* gB0 = W + (size_t)(bcol + srow) * K + kcsrc * 8;
  const ushort* gB1 = gB0 + (size_t)64 * K;

  auto stage = [&](int bf, int k0) {
    gload_lds16(gA0 + k0, &lA[bf][w * 512]);
    gload_lds16(gA1 + k0, &lA[bf][2048 + w * 512]);
    gload_lds16(gB0 + k0, &lB[bf][w * 512]);
    gload_lds16(gB1 + k0, &lB[bf][2048 + w * 512]);
  };

  const int frow = lane & 15;
  const int kq = lane >> 4;

  f32x4 acc[4][4];
  #pragma unroll
  for (int i = 0; i < 4; ++i)
    #pragma unroll
    for (int j = 0; j < 4; ++j) acc[i][j] = (f32x4){0.f, 0.f, 0.f, 0.f};

  stage(0, 0);
  __syncthreads();

  int buf = 0;
  for (int k0 = 0; k0 < K; k0 += 32, buf ^= 1) {
    if (k0 + 32 < K) stage(buf ^ 1, k0 + 32);

    bf16x8 af[4], bfr[4];
    #pragma unroll
    for (int mi = 0; mi < 4; ++mi) {
      int row = (wr << 6) + (mi << 4) + frow;
      int off = (row << 5) + ((kq ^ ((row >> 1) & 3)) << 3);
      af[mi] = *(const bf16x8*)&lA[buf][off];
    }
    #pragma unroll
    for (int ni = 0; ni < 4; ++ni) {
      int row = (wc << 6) + (ni << 4) + frow;
      int off = (row << 5) + ((kq ^ ((row >> 1) & 3)) << 3);
      bfr[ni] = *(const bf16x8*)&lB[buf][off];
    }
    #pragma unroll
    for (int mi = 0; mi < 4; ++mi)
      #pragma unroll
      for (int ni = 0; ni < 4; ++ni)
        acc[mi][ni] = __builtin_amdgcn_mfma_f32_16x16x32_bf16(
            af[mi], bfr[ni], acc[mi][ni], 0, 0, 0);
    __syncthreads();
  }

  // ---- epilogue: C row = rbase + r, col = bcol + wc*64 + ni*16 + frow ----
  #pragma unroll
  for (int mi = 0; mi < 4; ++mi) {
    const int rbase = brow + (wr << 6) + (mi << 4) + (kq << 2);
    float ss[4] = {0.f, 0.f, 0.f, 0.f};
    #pragma unroll
    for (int ni = 0; ni < 4; ++ni) {
      int col = bcol + (wc << 6) + (ni << 4) + frow;
      if (EPI == 0) {
        if (col < 1024) {
          #pragma unroll
          for (int r = 0; r < 4; ++r) {
            float v = acc[mi][ni][r];
            ((ushort*)outp)[(size_t)(rbase + r) * 1024 + col] =
                f2bf(__expf(-0.5f * v * v));
          }
        } else {
          bool isk = col < 2048;
          int c = col - (isk ? 1024 : 2048);
          int b = rbase >> 12, n = rbase & 4095;
          ushort4 o;
          #pragma unroll
          for (int r = 0; r < 4; ++r) {
            float v = acc[mi][ni][r];
            if (isk) v = __expf(-0.5f * v * v);
            ((ushort*)&o)[r] = f2bf(v);
          }
          ushort* dst = (isk ? kTp : vTp) +
                        ((size_t)(b * 16 + (c >> 6)) * 64 + (c & 63)) * 4096 + n;
          *(ushort4*)dst = o;
        }
      } else if (EPI == 1) {
        #pragma unroll
        for (int r = 0; r < 4; ++r) {
          size_t idx = (size_t)(rbase + r) * F + col;
          ((float*)outp)[idx] = resid[idx] + acc[mi][ni][r] + bias[col];
        }
      } else if (EPI == 2) {
        #pragma unroll
        for (int r = 0; r < 4; ++r) {
          float t2 = acc[mi][ni][r] * rowscale[rbase + r] + bias[col];
          float y = 0.79788456f * (t2 + 0.044715f * t2 * t2 * t2);
          float e = __expf(2.0f * y);
          float th = (e - 1.0f) / (e + 1.0f);
          ((ushort*)outp)[(size_t)(rbase + r) * F + col] =
              f2bf(0.5f * t2 * (1.0f + th));
        }
      } else {  // EPI 3
        #pragma unroll
        for (int r = 0; r < 4; ++r) {
          size_t idx = (size_t)(rbase + r) * F + col;
          float x1 = resid[idx] + acc[mi][ni][r] + bias[col];
          ((float*)outp)[idx] = x1;
          xnout[idx] = f2bf(x1 * escale[col]);
          ss[r] += x1 * x1;
        }
      }
    }
    if (EPI == 3) {
      // reduce ss over the 16 frow lanes (same rows, disjoint cols), 1 atomic/group
      #pragma unroll
      for (int r = 0; r < 4; ++r) {
        #pragma unroll
        for (int m = 1; m < 16; m <<= 1) ss[r] += __shfl_xor(ss[r], m);
      }
      if (frow == 0) {
        #pragma unroll
        for (int r = 0; r < 4; ++r) atomicAdd(&sumsq[rbase + r], ss[r]);
      }
    }
  }
}

// ---------------- kvT[b,h,e,d] = sum_n v[n,e]*k[n,d]  (MFMA, split-K) ----------------
__global__ __launch_bounds__(256)
void attn_kv_mfma(const ushort* __restrict__ kT, const ushort* __restrict__ vT,
                  float* __restrict__ kvT, float* __restrict__ ksum) {
  __shared__ float red[4][4096];
  int bi = blockIdx.x;
  int ksl = bi & 7, h = (bi >> 3) & 15, b = bi >> 7;
  int tid = threadIdx.x, lane = tid & 63, w = tid >> 6;
  int frow = lane & 15, kq = lane >> 4;
  const size_t bh = (size_t)(b * 16 + h) * 64;
  const ushort* vb = vT + bh * 4096;
  const ushort* kb = kT + bh * 4096;
  int tk0 = ksl * 512 + w * 128;

  f32x4 acc[4][4];
  #pragma unroll
  for (int i = 0; i < 4; ++i)
    #pragma unroll
    for (int j = 0; j < 4; ++j) acc[i][j] = (f32x4){0.f, 0.f, 0.f, 0.f};
  float kpart[4] = {0.f, 0.f, 0.f, 0.f};

  #pragma unroll
  for (int kstep = 0; kstep < 4; ++kstep) {
    int tok = tk0 + kstep * 32 + kq * 8;
    bf16x8 af[4], bfr[4];
    #pragma unroll
    for (int mi = 0; mi < 4; ++mi)
      af[mi] = *(const bf16x8*)&vb[(size_t)(mi * 16 + frow) * 4096 + tok];
    #pragma unroll
    for (int ni = 0; ni < 4; ++ni) {
      bfr[ni] = *(const bf16x8*)&kb[(size_t)(ni * 16 + frow) * 4096 + tok];
      #pragma unroll
      for (int j = 0; j < 8; ++j) kpart[ni] += bf2f((ushort)bfr[ni][j]);
    }
    #pragma unroll
    for (int mi = 0; mi < 4; ++mi)
      #pragma unroll
      for (int ni = 0; ni < 4; ++ni)
        acc[mi][ni] = __builtin_amdgcn_mfma_f32_16x16x32_bf16(
            af[mi], bfr[ni], acc[mi][ni], 0, 0, 0);
  }

  #pragma unroll
  for (int ni = 0; ni < 4; ++ni) {
    kpart[ni] += __shfl_xor(kpart[ni], 16);
    kpart[ni] += __shfl_xor(kpart[ni], 32);
  }
  if (lane < 16) {
    #pragma unroll
    for (int ni = 0; ni < 4; ++ni)
      atomicAdd(&ksum[(b * 16 + h) * 64 + ni * 16 + frow], kpart[ni]);
  }

  #pragma unroll
  for (int mi = 0; mi < 4; ++mi)
    #pragma unroll
    for (int ni = 0; ni < 4; ++ni)
      #pragma unroll
      for (int r = 0; r < 4; ++r)
        red[w][(mi * 16 + kq * 4 + r) * 64 + ni * 16 + frow] = acc[mi][ni][r];
  __syncthreads();
  float* kvg = kvT + (size_t)(b * 16 + h) * 4096;
  for (int i = tid; i < 4096; i += 256) {
    float s = red[0][i] + red[1][i] + red[2][i] + red[3][i];
    atomicAdd(&kvg[i], s);
  }
}

// ---------------- out[n,e] = z * sum_d q[n,d]*kvT[e,d]  (MFMA) ----------------
__global__ __launch_bounds__(256)
void attn_out_mfma(const ushort* __restrict__ qb, const float* __restrict__ kvT,
                   const float* __restrict__ ksum, ushort* __restrict__ ao) {
  __shared__ ushort skv[64 * 72];
  __shared__ float sks[64];
  int bi = blockIdx.x;
  int c = bi & 15, h = (bi >> 4) & 15, b = bi >> 8;
  int tid = threadIdx.x, lane = tid & 63, w = tid >> 6;
  int frow = lane & 15, kq = lane >> 4;
  const float* kvg = kvT + (size_t)(b * 16 + h) * 4096;
  for (int i = tid; i < 4096; i += 256)
    skv[(i >> 6) * 72 + (i & 63)] = f2bf(kvg[i]);
  if (tid < 64) sks[tid] = ksum[(b * 16 + h) * 64 + tid];
  __syncthreads();

  int m0 = b * 4096 + c * 256 + w * 64;
  f32x4 acc[4][4];
  #pragma unroll
  for (int i = 0; i < 4; ++i)
    #pragma unroll
    for (int j = 0; j < 4; ++j) acc[i][j] = (f32x4){0.f, 0.f, 0.f, 0.f};
  float dp[4] = {0.f, 0.f, 0.f, 0.f};

  #pragma unroll
  for (int kst = 0; kst < 2; ++kst) {
    int d0 = kst * 32 + kq * 8;
    bf16x8 af[4], bfr[4];
    #pragma unroll
    for (int mi = 0; mi < 4; ++mi)
      af[mi] = *(const bf16x8*)&qb[(size_t)(m0 + mi * 16 + frow) * 1024 + h * 64 + d0];
    #pragma unroll
    for (int ni = 0; ni < 4; ++ni)
      bfr[ni] = *(const bf16x8*)&skv[(ni * 16 + frow) * 72 + d0];
    #pragma unroll
    for (int mi = 0; mi < 4; ++mi) {
      float s = 0.f;
      #pragma unroll
      for (int j = 0; j < 8; ++j) s += bf2f((ushort)af[mi][j]) * sks[d0 + j];
      dp[mi] += s;
    }
    #pragma unroll
    for (int mi = 0; mi < 4; ++mi)
      #pragma unroll
      for (int ni = 0; ni < 4; ++ni)
        acc[mi][ni] = __builtin_amdgcn_mfma_f32_16x16x32_bf16(
            af[mi], bfr[ni], acc[mi][ni], 0, 0, 0);
  }

  #pragma unroll
  for (int mi = 0; mi < 4; ++mi) {
    dp[mi] += __shfl_xor(dp[mi], 16);
    dp[mi] += __shfl_xor(dp[mi], 32);
  }

  #pragma unroll
  for (int mi = 0; mi < 4; ++mi)
    #pragma unroll
    for (int ni = 0; ni < 4; ++ni)
      #pragma unroll
      for (int r = 0; r < 4; ++r) {
        float dotv = __shfl(dp[mi], (kq << 2) + r);
        float z = 1.f / (dotv + 1e-6f);
        int mrow = m0 + mi * 16 + kq * 4 + r;
        ao[(size_t)mrow * 1024 + h * 64 + ni * 16 + frow] =
            f2bf(acc[mi][ni][r] * z);
      }
}

extern "C" void kernel_launch(void* const* d_in, const int* in_sizes, int n_in,
                              void* d_out, int out_size, void* d_ws, size_t ws_size,
                              hipStream_t stream) {
  const float* x       = (const float*)d_in[0];
  const float* scale1  = (const float*)d_in[1];
  const float* scale2  = (const float*)d_in[2];
  const float* gamma   = (const float*)d_in[3];
  const float* qkv_w   = (const float*)d_in[4];
  const float* proj_w  = (const float*)d_in[5];
  const float* proj_b  = (const float*)d_in[6];
  const float* conv1_w = (const float*)d_in[7];
  const float* conv1_b = (const float*)d_in[8];
  const float* conv2_w = (const float*)d_in[9];
  const float* conv2_b = (const float*)d_in[10];
  float* out = (float*)d_out;

  char* ws = (char*)d_ws;
  size_t off = 0;
  auto alloc = [&](size_t bytes) {
    void* p = ws + off;
    off += (bytes + 255) & ~(size_t)255;
    return p;
  };
  ushort* xn     = (ushort*)alloc((size_t)MTOK * 1024 * 2);
  ushort* qb     = (ushort*)alloc((size_t)MTOK * 1024 * 2);
  ushort* kT     = (ushort*)alloc((size_t)MTOK * 1024 * 2);  // [b,h,d,n]
  ushort* vT     = (ushort*)alloc((size_t)MTOK * 1024 * 2);  // [b,h,e,n]
  ushort* attn_o = (ushort*)alloc((size_t)MTOK * 1024 * 2);
  float*  kvT    = (float*)alloc((size_t)(4 * 16 * 64 * 64 + 4 * 16 * 64) * 4);
  float*  ksum   = kvT + 4 * 16 * 64 * 64;
  ushort* wq = (ushort*)alloc((size_t)3072 * 1024 * 2);
  ushort* wp = (ushort*)alloc((size_t)1024 * 1024 * 2);
  ushort* w1 = (ushort*)alloc((size_t)2048 * 1024 * 2);
  ushort* w2 = (ushort*)alloc((size_t)1024 * 2048 * 2);
  float*  gbp = (float*)alloc(1024 * 4);     // gamma*proj_b
  float*  gbc = (float*)alloc(1024 * 4);     // gamma*conv2_b
  float*  sumsq = (float*)alloc(MTOK * 4);   // per-row sum(x1^2)
  float*  rnb   = (float*)alloc(MTOK * 4);   // rn per row
  ushort* hid = kT;   // [MTOK][2048] bf16 reuses kT+vT (dead after attention)
  if (off > ws_size) return;

  // one prep launch: converts + gamma folds + zero kvT/ksum/sumsq
  prep_k<<<8476, 256, 0, stream>>>(qkv_w, wq, proj_w, wp, conv1_w, w1, conv2_w, w2,
                                   gamma, proj_b, conv2_b, gbp, gbc, kvT, sumsq);

  // attention branch
  rmsnorm_k<<<MTOK, 256, 0, stream>>>(x, scale1, xn);
  gemm_bt<0><<<128 * 24, 256, 0, stream>>>(xn, wq, qb, nullptr, nullptr,
                                           kT, vT, nullptr, nullptr, nullptr, nullptr,
                                           MTOK, 3072, 1024);
  attn_kv_mfma<<<512, 256, 0, stream>>>(kT, vT, kvT, ksum);
  attn_out_mfma<<<1024, 256, 0, stream>>>(qb, kvT, ksum, attn_o);
  // proj + residual + fused norm-stats + xnraw (x1*scale2 bf16)
  gemm_bt<3><<<128 * 8, 256, 0, stream>>>(attn_o, wp, out, gbp, x,
                                          nullptr, nullptr, scale2, nullptr,
                                          sumsq, xn, MTOK, 1024, 1024);
  rn_k<<<64, 256, 0, stream>>>(sumsq, rnb, MTOK);

  // MLP branch (rn applied in conv1 epilogue; x1 lives in d_out)
  gemm_bt<2><<<128 * 16, 256, 0, stream>>>(xn, w1, hid, conv1_b, nullptr,
                                           nullptr, nullptr, nullptr, rnb,
                                           nullptr, nullptr, MTOK, 2048, 1024);
  gemm_bt<1><<<128 * 8, 256, 0, stream>>>(hid, w2, out, gbc, out,
                                          nullptr, nullptr, nullptr, nullptr,
                                          nullptr, nullptr, MTOK, 1024, 2048);
}